// Round 16
// baseline (51.679 us; speedup 1.0000x reference)
//
#include <hip/hip_runtime.h>

// TreeLoss: 2-level hierarchical softmax loss.
// z(b)    = 1 + sum_c e^{x_c + x_parent(c)} + sum_p e^{x_p}   (parents 56..63)
// loss(b) = log z - (x_g + x_parent(g)),  parent(g) = 56 + g/7; out = mean.
//
// R16: VGPR-direct, perfectly-coalesced, zero-LDS. A 16-lane group owns one
// row; lane j holds float4 chunk j (wave = 64 consecutive float4s = 1KB =
// the m13 copy-benchmark access pattern). Parents (chunks 14,15) broadcast
// intra-group via 8 shuffles; each child element adds its parent before a
// single exp. The marginal x_g + x_parent(g) requires NO gather: each lane
// contributes its own element iff it holds node g or parent(g), summed in
// the same dual 16-lane butterfly as z. Tests whether the session-wide
// ~4.2 TB/s read pin is an LDS-staging artifact or a true read ceiling
// (R6's VGPR attempt was confounded: 64 distinct lines/instr, L1 thrash).

#define THREADS 512               // 8 waves
#define BLOCKS  1024              // 4 blocks/CU, 32 waves/CU, one generation

__device__ __forceinline__ float esel(const float4& v, int k) {
    return (k & 2) ? ((k & 1) ? v.w : v.z) : ((k & 1) ? v.y : v.x);
}
// Select parent scalar P[idx] from the two broadcast parent chunks.
// idx may exceed 7 for parent-chunk lanes; result is zero-masked there.
__device__ __forceinline__ float psel(int idx, const float4& vp0, const float4& vp1) {
    return idx < 4 ? ((idx < 2) ? ((idx & 1) ? vp0.y : vp0.x)
                                : ((idx & 1) ? vp0.w : vp0.z))
                   : ((idx < 6) ? ((idx & 1) ? vp1.y : vp1.x)
                                : ((idx & 1) ? vp1.w : vp1.z));
}

__global__ void __launch_bounds__(THREADS) tree_loss_partial(
    const float* __restrict__ pred,   // [rows, 64]
    const int*   __restrict__ gt,     // [rows] 0..55
    float*       __restrict__ partial,// [nwaves]
    int rows)
{
    const int l     = threadIdx.x & 63;
    const int j     = l & 15;              // chunk within row
    const int gbase = l & ~15;             // group base lane (shfl source calc)
    const int waveG = (int)blockIdx.x * (THREADS >> 6) + (threadIdx.x >> 6);
    const int nwaves = BLOCKS * (THREADS >> 6);   // 8192

    const float4* p4 = (const float4*)pred;
    const int n0 = j << 2;                 // first node of this chunk
    const int a  = n0 / 7;                 // boundary parents (compile: magic mul)
    const int b  = (n0 + 3) / 7;
    const int nb = 7 * b;

    float acc = 0.f;
    const int nIt = (rows + 3) >> 2;       // 4 rows per wave-iteration
    for (int it = waveG; it < nIt; it += nwaves) {
        const int row   = (it << 2) + (l >> 4);
        const bool valid = row < rows;
        const int rclmp = valid ? row : rows - 1;
        const float4 v = p4[(size_t)rclmp * 16 + j];   // 1KB/wave, contiguous
        const int g = gt[rclmp];                        // group-uniform bcast

        // Broadcast parent chunks from lanes gbase+14 / gbase+15.
        float4 vp0, vp1;
        vp0.x = __shfl(v.x, gbase + 14); vp0.y = __shfl(v.y, gbase + 14);
        vp0.z = __shfl(v.z, gbase + 14); vp0.w = __shfl(v.w, gbase + 14);
        vp1.x = __shfl(v.x, gbase + 15); vp1.y = __shfl(v.y, gbase + 15);
        vp1.z = __shfl(v.z, gbase + 15); vp1.w = __shfl(v.w, gbase + 15);

        const float A = psel(a, vp0, vp1);
        const float B = psel(b, vp0, vp1);

        // z partial: children add their parent logit pre-exp; parent elems
        // (node>=56) add 0 -> contribute e^{x_p}. Branch-free.
        float zp = 0.f;
        #pragma unroll
        for (int k = 0; k < 4; ++k) {
            const int node = n0 + k;
            float pa = (node < nb) ? A : B;
            pa = (node < 56) ? pa : 0.f;
            zp += __expf(esel(v, k) + pa);
        }

        // Marginal partial: own-element contributions, no gather.
        const int wp = 56 + g / 7;
        float mg = 0.f;
        mg += ((g  >> 2) == j) ? esel(v, g  & 3) : 0.f;
        mg += ((wp >> 2) == j) ? esel(v, wp & 3) : 0.f;

        // Dual 16-lane butterfly (masks < 16 stay within the group).
        float z16 = zp, m16 = mg;
        #pragma unroll
        for (int m = 8; m; m >>= 1) {
            z16 += __shfl_xor(z16, m);
            m16 += __shfl_xor(m16, m);
        }
        const float loss = __logf(1.f + z16) - m16;
        acc += (j == 0 && valid) ? loss : 0.f;
    }

    // 64-lane reduce (only j==0 lanes carry nonzero).
    #pragma unroll
    for (int off = 32; off; off >>= 1) acc += __shfl_xor(acc, off);
    if (l == 0) partial[waveG] = acc;
}

__global__ void __launch_bounds__(1024) tree_loss_final(
    const float4* __restrict__ p4, int n4,
    float* __restrict__ out, float inv)
{
    float s = 0.0f;
    for (int i = threadIdx.x; i < n4; i += 1024) {
        const float4 v = p4[i];
        s += (v.x + v.y) + (v.z + v.w);
    }
    #pragma unroll
    for (int off = 32; off; off >>= 1) s += __shfl_xor(s, off);
    __shared__ float w[16];
    const int lane = threadIdx.x & 63;
    const int wv   = threadIdx.x >> 6;
    if (lane == 0) w[wv] = s;
    __syncthreads();
    if (threadIdx.x == 0) {
        float b = 0.f;
        #pragma unroll
        for (int k = 0; k < 16; ++k) b += w[k];
        out[0] = b * inv;
    }
}

extern "C" void kernel_launch(void* const* d_in, const int* in_sizes, int n_in,
                              void* d_out, int out_size, void* d_ws, size_t ws_size,
                              hipStream_t stream) {
    const float* pred = (const float*)d_in[0];   // [B,64] fp32
    const int*   gt   = (const int*)d_in[1];     // [B] int32
    float* out     = (float*)d_out;
    float* partial = (float*)d_ws;
    const int rows = in_sizes[1];                // BATCH = 262144

    const int nwaves = BLOCKS * (THREADS >> 6);  // 8192 partials (32KB ws)
    tree_loss_partial<<<BLOCKS, THREADS, 0, stream>>>(pred, gt, partial, rows);
    tree_loss_final<<<1, 1024, 0, stream>>>((const float4*)partial, nwaves / 4,
                                            out, 1.0f / (float)rows);
}